// Round 2
// baseline (1068.806 us; speedup 1.0000x reference)
//
#include <hip/hip_runtime.h>
#include <math.h>

#define H 128
#define NHD 8
#define DH 16
#define RB 6
#define NBI 2
#define BSG 16
#define LBLK 64
#define KATOM 16
#define NBLKT 1024
#define NA 16384
#define NE 262144
#define EBE 512

__device__ __forceinline__ float atomAddF(float* p, float v) {
#if defined(__gfx90a__) || defined(__gfx940__) || defined(__gfx941__) || defined(__gfx942__) || defined(__gfx950__)
  return unsafeAtomicAdd(p, v);
#else
  return atomicAdd(p, v);
#endif
}

// ---------------- embedding ----------------
__global__ __launch_bounds__(256) void k_embed(
    const int* __restrict__ A, const int* __restrict__ apos,
    const int* __restrict__ btypes,
    const float* __restrict__ emb_atom, const float* __restrict__ emb_pos,
    const float* __restrict__ emb_block, float* __restrict__ x)
{
  int idx = blockIdx.x * 256 + threadIdx.x;   // over NA*H
  int n = idx >> 7, h = idx & 127;
  x[idx] = emb_atom[A[n] * H + h] + emb_pos[apos[n] * H + h]
         + emb_block[btypes[n >> 4] * H + h];
}

// ---------------- rbf + edge counts ----------------
__global__ __launch_bounds__(256) void k_rbf(
    const int* __restrict__ ei, const int* __restrict__ ej,
    const float* __restrict__ coords, const float* __restrict__ freq,
    float* __restrict__ rbf, float* __restrict__ cntf)
{
  int e = blockIdx.x * 256 + threadIdx.x;
  int i = ei[e], j = ej[e];
  float dx = coords[i*3+0] - coords[j*3+0];
  float dy = coords[i*3+1] - coords[j*3+1];
  float dz = coords[i*3+2] - coords[j*3+2];
  float d = sqrtf(dx*dx + dy*dy + dz*dz);
  float u = fmaxf(d * 0.125f, 1e-3f);
  float u2 = u*u, u4 = u2*u2, u5 = u4*u, u6 = u5*u, u7 = u6*u;
  float env = 1.0f/u - 28.0f*u5 + 48.0f*u6 - 21.0f*u7;
  #pragma unroll
  for (int r = 0; r < RB; ++r)
    rbf[(size_t)e*RB + r] = env * sinf(freq[r] * u);
  atomAddF(&cntf[i], 1.0f);
}

// ---------------- per-edge hidden + scatter ----------------
__global__ __launch_bounds__(256) void k_edge_pass(
    const float* __restrict__ P, const float* __restrict__ Q,
    const float* __restrict__ rbf, const float* __restrict__ W1c,
    const int* __restrict__ ei, const int* __restrict__ ej,
    float* __restrict__ Hagg)
{
  __shared__ float w[RB * H];
  for (int idx = threadIdx.x; idx < RB * H; idx += 256) w[idx] = W1c[idx];
  __syncthreads();
  int c = threadIdx.x & 127, sub = threadIdx.x >> 7;
  int e0 = blockIdx.x * 16 + sub * 8;
  for (int t = 0; t < 8; ++t) {
    int e = e0 + t;
    int i = ei[e], j = ej[e];
    float v = P[(size_t)i*H + c] + Q[(size_t)j*H + c];
    #pragma unroll
    for (int r = 0; r < RB; ++r)
      v += rbf[(size_t)e*RB + r] * w[r*H + c];
    float hv = v / (1.0f + expf(-v));   // silu
    atomAddF(&Hagg[(size_t)i*H + c], hv);
  }
}

// ---------------- generic 128-col GEMM ----------------
// C[m, ccol0+c] = act( (A1|A2)[m,:] @ W[:, wcol0+c] + bias[c]*bias_scale[m] ) + res[m,c]
__global__ __launch_bounds__(256) void gemm128(
    const float* __restrict__ A1, const float* __restrict__ A2,
    const float* __restrict__ W, int ldw, int wcol0,
    const float* __restrict__ bias, const float* __restrict__ bias_scale,
    const float* __restrict__ res,
    float* __restrict__ C, int ldc, int ccol0,
    int M, int Ktot, int act)
{
  __shared__ float As[32][256];
  __shared__ float Ws[16][128];
  int tid = threadIdx.x;
  int m0 = blockIdx.x * 32;
  for (int idx = tid; idx < 32*32; idx += 256) {
    int r = idx >> 5, k4 = idx & 31;
    float4 v = *(const float4*)&A1[(size_t)(m0 + r)*H + k4*4];
    *(float4*)&As[r][k4*4] = v;
  }
  if (A2) {
    for (int idx = tid; idx < 32*32; idx += 256) {
      int r = idx >> 5, k4 = idx & 31;
      float4 v = *(const float4*)&A2[(size_t)(m0 + r)*H + k4*4];
      *(float4*)&As[r][128 + k4*4] = v;
    }
  }
  int rr = tid >> 5;    // 0..7
  int cq = tid & 31;    // col quad
  float acc[4][4] = {};
  for (int kk0 = 0; kk0 < Ktot; kk0 += 16) {
    __syncthreads();
    for (int idx = tid; idx < 16*32; idx += 256) {
      int kr = idx >> 5, c4 = idx & 31;
      float4 v = *(const float4*)&W[(size_t)(kk0 + kr)*ldw + wcol0 + c4*4];
      *(float4*)&Ws[kr][c4*4] = v;
    }
    __syncthreads();
    #pragma unroll
    for (int kr = 0; kr < 16; ++kr) {
      float4 w = *(const float4*)&Ws[kr][cq*4];
      #pragma unroll
      for (int i = 0; i < 4; ++i) {
        float a = As[rr + 8*i][kk0 + kr];
        acc[i][0] += a * w.x; acc[i][1] += a * w.y;
        acc[i][2] += a * w.z; acc[i][3] += a * w.w;
      }
    }
  }
  #pragma unroll
  for (int i = 0; i < 4; ++i) {
    int m = m0 + rr + 8*i;
    float bs = bias_scale ? bias_scale[m] : 1.0f;
    float4 out;
    float* po = &out.x;
    #pragma unroll
    for (int j = 0; j < 4; ++j) {
      int c = cq*4 + j;
      float v = acc[i][j];
      if (bias) v += bias[c] * bs;
      if (act == 1) v = v / (1.0f + expf(-v));
      else if (act == 2) v = fmaxf(v, 0.0f);
      if (res) v += res[(size_t)m*H + c];
      po[j] = v;
    }
    *(float4*)&C[(size_t)m*ldc + ccol0 + cq*4] = out;
  }
}

// ---------------- block mean over K atoms ----------------
__global__ __launch_bounds__(256) void k_block_mean(
    const float* __restrict__ x, float* __restrict__ blocks)
{
  int idx = blockIdx.x * 256 + threadIdx.x;   // over NBLKT*H
  int nb = idx >> 7, h = idx & 127;
  float s = 0.0f;
  #pragma unroll
  for (int k = 0; k < KATOM; ++k)
    s += x[(size_t)(nb*KATOM + k)*H + h];
  blocks[idx] = s * (1.0f / KATOM);
}

// ---------------- block-edge pre-activation gather ----------------
__global__ __launch_bounds__(256) void k_gather_pre(
    const float* __restrict__ Pb, const float* __restrict__ Qb,
    const int* __restrict__ bedges, float* __restrict__ Epre)
{
  int idx = blockIdx.x * 256 + threadIdx.x;   // over BSG*EBE*H
  int row = idx >> 7, c = idx & 127;
  int g = row >> 9;
  int src = bedges[row*2], dst = bedges[row*2 + 1];
  float v = Pb[(size_t)(g*LBLK + src)*H + c] + Qb[(size_t)(g*LBLK + dst)*H + c];
  Epre[idx] = fmaxf(v, 0.0f);
}

__global__ __launch_bounds__(256) void k_cntb(
    const int* __restrict__ bedges, float* __restrict__ cntb)
{
  int idx = blockIdx.x * 256 + threadIdx.x;   // over BSG*EBE
  int g = idx >> 9;
  int src = bedges[idx*2];
  atomAddF(&cntb[g*LBLK + src], 1.0f);
}

// ---------------- MHA core: one (batch, head) per block ----------------
// mode 0: scatter-add per-row head-output into bsum[seg] (seg from block_edges src)
// mode 1: add head-output/64 into m2[b]  (mean over sequence)
__global__ __launch_bounds__(256) void k_attn(
    const float* __restrict__ qkv, int S,
    const int* __restrict__ bedges,
    float* __restrict__ outbuf, int mode)
{
  extern __shared__ float smem[];
  float* Ks = smem;
  float* Vs = smem + (size_t)S * DH;
  int b = blockIdx.x >> 3, h = blockIdx.x & 7;
  int tid = threadIdx.x;
  const float* base = qkv + (size_t)b * S * 384;
  for (int idx = tid; idx < S * DH; idx += 256) {
    int s = idx >> 4, d = idx & 15;
    Ks[idx] = base[(size_t)s*384 + 128 + h*DH + d];
    Vs[idx] = base[(size_t)s*384 + 256 + h*DH + d];
  }
  __syncthreads();
  for (int s = tid; s < S; s += 256) {
    float q[DH];
    #pragma unroll
    for (int d = 0; d < DH; ++d) q[d] = base[(size_t)s*384 + h*DH + d];
    float mx = -1e30f, l = 0.0f, o[DH] = {};
    for (int j = 0; j < S; ++j) {
      float sc = 0.0f;
      #pragma unroll
      for (int d = 0; d < DH; ++d) sc += q[d] * Ks[j*DH + d];
      sc *= 0.25f;   // 1/sqrt(16)
      float mn = fmaxf(mx, sc);
      float corr = expf(mx - mn);
      float p = expf(sc - mn);
      l = l * corr + p;
      #pragma unroll
      for (int d = 0; d < DH; ++d) o[d] = o[d] * corr + p * Vs[j*DH + d];
      mx = mn;
    }
    float inv = 1.0f / l;
    if (mode == 0) {
      int src = bedges[((size_t)b*EBE + s)*2];
      float* dst = outbuf + ((size_t)(b*LBLK + src)*H + h*DH);
      #pragma unroll
      for (int d = 0; d < DH; ++d) atomAddF(&dst[d], o[d] * inv);
    } else {
      float* dst = outbuf + (size_t)b*H + h*DH;
      #pragma unroll
      for (int d = 0; d < DH; ++d) atomAddF(&dst[d], o[d] * inv * (1.0f/64.0f));
    }
  }
}

__global__ __launch_bounds__(256) void k_scale_bsum(
    float* __restrict__ bsum, const float* __restrict__ cntb,
    float* __restrict__ ind)
{
  int idx = blockIdx.x * 256 + threadIdx.x;   // over NBLKT*H
  int r = idx >> 7;
  float c = cntb[r];
  bsum[idx] = (c > 0.0f) ? bsum[idx] / c : 0.0f;
  if ((idx & 127) == 0) ind[r] = (c > 0.0f) ? 1.0f : 0.0f;
}

// ---------------- final: out-proj + LN + 3-layer MLP ----------------
__device__ __forceinline__ float bsum128(float v, float* red) {
  int t = threadIdx.x;
  red[t] = v; __syncthreads();
  #pragma unroll
  for (int off = 64; off > 0; off >>= 1) {
    if (t < off) red[t] += red[t + off];
    __syncthreads();
  }
  float s = red[0];
  __syncthreads();
  return s;
}

__global__ __launch_bounds__(128) void k_final(
    const float* __restrict__ m2, const float* __restrict__ out_w,
    const float* __restrict__ out_b, const float* __restrict__ lng,
    const float* __restrict__ lnb, const float* __restrict__ w1,
    const float* __restrict__ b1, const float* __restrict__ w2,
    const float* __restrict__ b2, const float* __restrict__ w3,
    const float* __restrict__ b3, float* __restrict__ out)
{
  __shared__ float buf[128];
  __shared__ float red[128];
  int b = blockIdx.x, t = threadIdx.x;
  buf[t] = m2[b*H + t];
  __syncthreads();
  float g = out_b[t];
  for (int k = 0; k < H; ++k) g += buf[k] * out_w[k*H + t];
  float mu = bsum128(g, red) * (1.0f / H);
  float df = g - mu;
  float var = bsum128(df * df, red) * (1.0f / H);
  float gn = df / sqrtf(var + 1e-5f) * lng[t] + lnb[t];
  __syncthreads();
  buf[t] = gn; __syncthreads();
  float h1 = b1[t];
  for (int k = 0; k < H; ++k) h1 += buf[k] * w1[k*H + t];
  h1 = fmaxf(h1, 0.0f);
  __syncthreads();
  buf[t] = h1; __syncthreads();
  float h2 = b2[t];
  for (int k = 0; k < H; ++k) h2 += buf[k] * w2[k*H + t];
  h2 = fmaxf(h2, 0.0f);
  float tot = bsum128(h2 * w3[t], red);
  if (t == 0) out[b] = tot + b3[0];
}

extern "C" void kernel_launch(void* const* d_in, const int* in_sizes, int n_in,
                              void* d_out, int out_size, void* d_ws, size_t ws_size,
                              hipStream_t stream) {
  (void)in_sizes; (void)n_in; (void)out_size; (void)ws_size;
  const int*   A          = (const int*)d_in[0];
  const int*   apos       = (const int*)d_in[1];
  const int*   btypes     = (const int*)d_in[2];
  const float* coords     = (const float*)d_in[3];
  const int*   edge_index = (const int*)d_in[4];
  const int*   bedges     = (const int*)d_in[5];
  const float* emb_atom   = (const float*)d_in[6];
  const float* emb_pos    = (const float*)d_in[7];
  const float* emb_block  = (const float*)d_in[8];
  const float* rbf_freq   = (const float*)d_in[9];
  const float* inter_w1   = (const float*)d_in[10];
  const float* inter_b1   = (const float*)d_in[11];
  const float* inter_w2   = (const float*)d_in[12];
  const float* inter_b2   = (const float*)d_in[13];
  const float* upd_w1     = (const float*)d_in[14];
  const float* upd_b1     = (const float*)d_in[15];
  const float* upd_w2     = (const float*)d_in[16];
  const float* upd_b2     = (const float*)d_in[17];
  const float* edge_w1    = (const float*)d_in[18];
  const float* edge_b1    = (const float*)d_in[19];
  const float* edge_w2    = (const float*)d_in[20];
  const float* edge_b2    = (const float*)d_in[21];
  const float* attn_in_w  = (const float*)d_in[22];
  const float* attn_in_b  = (const float*)d_in[23];
  const float* attn_out_w = (const float*)d_in[24];
  const float* attn_out_b = (const float*)d_in[25];
  const float* ln_g       = (const float*)d_in[26];
  const float* ln_b       = (const float*)d_in[27];
  const float* fin_w1     = (const float*)d_in[28];
  const float* fin_b1     = (const float*)d_in[29];
  const float* fin_w2     = (const float*)d_in[30];
  const float* fin_b2     = (const float*)d_in[31];
  const float* fin_w3     = (const float*)d_in[32];
  const float* fin_b3     = (const float*)d_in[33];
  float* out = (float*)d_out;

  float* ws = (float*)d_ws;
  float* x      = ws + 0;
  float* P      = ws + 2097152;
  float* Q      = ws + 4194304;
  float* Hagg   = ws + 6291456;
  float* rbf    = ws + 8388608;    // E*6
  float* cntf   = ws + 9961472;    // NA
  float* blocks = ws + 9977856;    // NBLKT*H
  float* Pb     = ws + 10108928;
  float* Qb     = ws + 10240000;
  float* Epre   = ws + 10371072;   // BSG*EBE*H
  float* ef2    = ws + 11419648;
  float* qkv    = ws + 12468224;   // BSG*EBE*384 (reused for qkv2)
  float* bsum   = ws + 15613952;   // NBLKT*H
  float* cntb   = ws + 15745024;   // NBLKT
  float* ind    = ws + 15746048;   // NBLKT
  float* m2     = ws + 15747072;   // BSG*H

  const int* ei = edge_index;
  const int* ej = edge_index + NE;

  (void)hipMemsetAsync(cntf, 0, NA * sizeof(float), stream);
  k_embed<<<NA*H/256, 256, 0, stream>>>(A, apos, btypes, emb_atom, emb_pos, emb_block, x);
  k_rbf<<<NE/256, 256, 0, stream>>>(ei, ej, coords, rbf_freq, rbf, cntf);

  for (int b = 0; b < NBI; ++b) {
    const float* w1 = inter_w1 + (size_t)b * 262 * H;
    // P = x@W1a + b1 ; Q = x@W1b
    gemm128<<<NA/32, 256, 0, stream>>>(x, nullptr, w1, H, 0, inter_b1 + b*H,
                                       nullptr, nullptr, P, H, 0, NA, H, 0);
    gemm128<<<NA/32, 256, 0, stream>>>(x, nullptr, w1 + 128*H, H, 0, nullptr,
                                       nullptr, nullptr, Q, H, 0, NA, H, 0);
    (void)hipMemsetAsync(Hagg, 0, (size_t)NA * H * sizeof(float), stream);
    k_edge_pass<<<NE/16, 256, 0, stream>>>(P, Q, rbf, w1 + 256*H, ei, ej, Hagg);
    // agg = Hagg@W2 + cnt*b2  -> into P
    gemm128<<<NA/32, 256, 0, stream>>>(Hagg, nullptr, inter_w2 + (size_t)b*H*H, H, 0,
                                       inter_b2 + b*H, cntf, nullptr, P, H, 0, NA, H, 0);
    // U = silu([x|agg]@upd_w1 + b1) -> into Q
    gemm128<<<NA/32, 256, 0, stream>>>(x, P, upd_w1 + (size_t)b*2*H*H, H, 0,
                                       upd_b1 + b*H, nullptr, nullptr, Q, H, 0, NA, 2*H, 1);
    // x = U@upd_w2 + b2 + x
    gemm128<<<NA/32, 256, 0, stream>>>(Q, nullptr, upd_w2 + (size_t)b*H*H, H, 0,
                                       upd_b2 + b*H, nullptr, x, x, H, 0, NA, H, 0);
  }

  k_block_mean<<<NBLKT*H/256, 256, 0, stream>>>(x, blocks);
  gemm128<<<NBLKT/32, 256, 0, stream>>>(blocks, nullptr, edge_w1, H, 0, edge_b1,
                                        nullptr, nullptr, Pb, H, 0, NBLKT, H, 0);
  gemm128<<<NBLKT/32, 256, 0, stream>>>(blocks, nullptr, edge_w1 + 128*H, H, 0, nullptr,
                                        nullptr, nullptr, Qb, H, 0, NBLKT, H, 0);
  k_gather_pre<<<BSG*EBE*H/256, 256, 0, stream>>>(Pb, Qb, bedges, Epre);
  gemm128<<<BSG*EBE/32, 256, 0, stream>>>(Epre, nullptr, edge_w2, H, 0, edge_b2,
                                          nullptr, nullptr, ef2, H, 0, BSG*EBE, H, 0);
  for (int c0 = 0; c0 < 384; c0 += 128)
    gemm128<<<BSG*EBE/32, 256, 0, stream>>>(ef2, nullptr, attn_in_w, 384, c0,
                                            attn_in_b + c0, nullptr, nullptr,
                                            qkv, 384, c0, BSG*EBE, H, 0);
  (void)hipMemsetAsync(bsum, 0, (size_t)(131072 + 1024 + 1024 + 2048) * sizeof(float), stream);
  k_cntb<<<BSG*EBE/256, 256, 0, stream>>>(bedges, cntb);
  k_attn<<<BSG*NHD, 256, (size_t)EBE*DH*2*sizeof(float), stream>>>(qkv, EBE, bedges, bsum, 0);
  k_scale_bsum<<<NBLKT*H/256, 256, 0, stream>>>(bsum, cntb, ind);
  // blocks += (bsum/cnt)@out_w + out_b*[cnt>0]
  gemm128<<<NBLKT/32, 256, 0, stream>>>(bsum, nullptr, attn_out_w, H, 0, attn_out_b,
                                        ind, blocks, blocks, H, 0, NBLKT, H, 0);
  for (int c0 = 0; c0 < 384; c0 += 128)
    gemm128<<<NBLKT/32, 256, 0, stream>>>(blocks, nullptr, attn_in_w, 384, c0,
                                          attn_in_b + c0, nullptr, nullptr,
                                          qkv, 384, c0, NBLKT, H, 0);
  k_attn<<<BSG*NHD, 256, (size_t)LBLK*DH*2*sizeof(float), stream>>>(qkv, LBLK, nullptr, m2, 1);
  k_final<<<BSG, 128, 0, stream>>>(m2, attn_out_w, attn_out_b, ln_g, ln_b,
                                   fin_w1, fin_b1, fin_w2, fin_b2, fin_w3, fin_b3, out);
}

// Round 3
// 1040.029 us; speedup vs baseline: 1.0277x; 1.0277x over previous
//
#include <hip/hip_runtime.h>
#include <math.h>

#define H 128
#define NHD 8
#define DH 16
#define RB 6
#define NBI 2
#define BSG 16
#define LBLK 64
#define KATOM 16
#define NBLKT 1024
#define NA 16384
#define NE 262144
#define EBE 512

__device__ __forceinline__ float atomAddF(float* p, float v) {
#if defined(__gfx90a__) || defined(__gfx940__) || defined(__gfx941__) || defined(__gfx942__) || defined(__gfx950__)
  return unsafeAtomicAdd(p, v);
#else
  return atomicAdd(p, v);
#endif
}

// ---------------- embedding ----------------
__global__ __launch_bounds__(256) void k_embed(
    const int* __restrict__ A, const int* __restrict__ apos,
    const int* __restrict__ btypes,
    const float* __restrict__ emb_atom, const float* __restrict__ emb_pos,
    const float* __restrict__ emb_block, float* __restrict__ x)
{
  int idx = blockIdx.x * 256 + threadIdx.x;   // over NA*H
  int n = idx >> 7, h = idx & 127;
  x[idx] = emb_atom[A[n] * H + h] + emb_pos[apos[n] * H + h]
         + emb_block[btypes[n >> 4] * H + h];
}

// ---------------- rbf + edge counts ----------------
__global__ __launch_bounds__(256) void k_rbf(
    const int* __restrict__ ei, const int* __restrict__ ej,
    const float* __restrict__ coords, const float* __restrict__ freq,
    float* __restrict__ rbf, float* __restrict__ cntf)
{
  int e = blockIdx.x * 256 + threadIdx.x;
  int i = ei[e], j = ej[e];
  float dx = coords[i*3+0] - coords[j*3+0];
  float dy = coords[i*3+1] - coords[j*3+1];
  float dz = coords[i*3+2] - coords[j*3+2];
  float d = sqrtf(dx*dx + dy*dy + dz*dz);
  float u = fmaxf(d * 0.125f, 1e-3f);
  float u2 = u*u, u4 = u2*u2, u5 = u4*u, u6 = u5*u, u7 = u6*u;
  float env = 1.0f/u - 28.0f*u5 + 48.0f*u6 - 21.0f*u7;
  #pragma unroll
  for (int r = 0; r < RB; ++r)
    rbf[(size_t)e*RB + r] = env * sinf(freq[r] * u);
  atomAddF(&cntf[i], 1.0f);
}

// ---------------- per-edge hidden + scatter ----------------
__global__ __launch_bounds__(256) void k_edge_pass(
    const float* __restrict__ P, const float* __restrict__ Q,
    const float* __restrict__ rbf, const float* __restrict__ W1c,
    const int* __restrict__ ei, const int* __restrict__ ej,
    float* __restrict__ Hagg)
{
  __shared__ float w[RB * H];
  for (int idx = threadIdx.x; idx < RB * H; idx += 256) w[idx] = W1c[idx];
  __syncthreads();
  int c = threadIdx.x & 127, sub = threadIdx.x >> 7;
  int e0 = blockIdx.x * 16 + sub * 8;
  for (int t = 0; t < 8; ++t) {
    int e = e0 + t;
    int i = ei[e], j = ej[e];
    float v = P[(size_t)i*H + c] + Q[(size_t)j*H + c];
    #pragma unroll
    for (int r = 0; r < RB; ++r)
      v += rbf[(size_t)e*RB + r] * w[r*H + c];
    float hv = v / (1.0f + expf(-v));   // silu
    atomAddF(&Hagg[(size_t)i*H + c], hv);
  }
}

// ---------------- generic 128-col GEMM ----------------
// C[m, ccol0+c] = act( (A1|A2)[m,:] @ W[:, wcol0+c] + bias[c]*bias_scale[m] ) + res[m,c]
__global__ __launch_bounds__(256) void gemm128(
    const float* __restrict__ A1, const float* __restrict__ A2,
    const float* __restrict__ W, int ldw, int wcol0,
    const float* __restrict__ bias, const float* __restrict__ bias_scale,
    const float* __restrict__ res,
    float* __restrict__ C, int ldc, int ccol0,
    int M, int Ktot, int act)
{
  __shared__ float As[32][256];
  __shared__ float Ws[16][128];
  int tid = threadIdx.x;
  int m0 = blockIdx.x * 32;
  for (int idx = tid; idx < 32*32; idx += 256) {
    int r = idx >> 5, k4 = idx & 31;
    float4 v = *(const float4*)&A1[(size_t)(m0 + r)*H + k4*4];
    *(float4*)&As[r][k4*4] = v;
  }
  if (A2) {
    for (int idx = tid; idx < 32*32; idx += 256) {
      int r = idx >> 5, k4 = idx & 31;
      float4 v = *(const float4*)&A2[(size_t)(m0 + r)*H + k4*4];
      *(float4*)&As[r][128 + k4*4] = v;
    }
  }
  int rr = tid >> 5;    // 0..7
  int cq = tid & 31;    // col quad
  float acc[4][4] = {};
  for (int kk0 = 0; kk0 < Ktot; kk0 += 16) {
    __syncthreads();
    for (int idx = tid; idx < 16*32; idx += 256) {
      int kr = idx >> 5, c4 = idx & 31;
      float4 v = *(const float4*)&W[(size_t)(kk0 + kr)*ldw + wcol0 + c4*4];
      *(float4*)&Ws[kr][c4*4] = v;
    }
    __syncthreads();
    #pragma unroll
    for (int kr = 0; kr < 16; ++kr) {
      float4 w = *(const float4*)&Ws[kr][cq*4];
      #pragma unroll
      for (int i = 0; i < 4; ++i) {
        float a = As[rr + 8*i][kk0 + kr];
        acc[i][0] += a * w.x; acc[i][1] += a * w.y;
        acc[i][2] += a * w.z; acc[i][3] += a * w.w;
      }
    }
  }
  #pragma unroll
  for (int i = 0; i < 4; ++i) {
    int m = m0 + rr + 8*i;
    float bs = bias_scale ? bias_scale[m] : 1.0f;
    float4 out;
    float* po = &out.x;
    #pragma unroll
    for (int j = 0; j < 4; ++j) {
      int c = cq*4 + j;
      float v = acc[i][j];
      if (bias) v += bias[c] * bs;
      if (act == 1) v = v / (1.0f + expf(-v));
      else if (act == 2) v = fmaxf(v, 0.0f);
      if (res) v += res[(size_t)m*H + c];
      po[j] = v;
    }
    *(float4*)&C[(size_t)m*ldc + ccol0 + cq*4] = out;
  }
}

// ---------------- block mean over K atoms ----------------
__global__ __launch_bounds__(256) void k_block_mean(
    const float* __restrict__ x, float* __restrict__ blocks)
{
  int idx = blockIdx.x * 256 + threadIdx.x;   // over NBLKT*H
  int nb = idx >> 7, h = idx & 127;
  float s = 0.0f;
  #pragma unroll
  for (int k = 0; k < KATOM; ++k)
    s += x[(size_t)(nb*KATOM + k)*H + h];
  blocks[idx] = s * (1.0f / KATOM);
}

// ---------------- block-edge pre-activation gather ----------------
__global__ __launch_bounds__(256) void k_gather_pre(
    const float* __restrict__ Pb, const float* __restrict__ Qb,
    const int* __restrict__ bedges, float* __restrict__ Epre)
{
  int idx = blockIdx.x * 256 + threadIdx.x;   // over BSG*EBE*H
  int row = idx >> 7, c = idx & 127;
  int g = row >> 9;
  int src = bedges[row*2], dst = bedges[row*2 + 1];
  float v = Pb[(size_t)(g*LBLK + src)*H + c] + Qb[(size_t)(g*LBLK + dst)*H + c];
  Epre[idx] = fmaxf(v, 0.0f);
}

__global__ __launch_bounds__(256) void k_cntb(
    const int* __restrict__ bedges, float* __restrict__ cntb)
{
  int idx = blockIdx.x * 256 + threadIdx.x;   // over BSG*EBE
  int g = idx >> 9;
  int src = bedges[idx*2];
  atomAddF(&cntb[g*LBLK + src], 1.0f);
}

// ---------------- MHA: wave-per-row, two-pass softmax ----------------
// MODE 0: scatter-add per-row head-output into outbuf[(b*LBLK+src)*H + h*16+d]
// MODE 1: add head-output/64 into outbuf[b*H + h*16+d]
template <int S, int RPB, int MODE>
__global__ __launch_bounds__(256) void k_attn2(
    const float* __restrict__ qkv,
    const int* __restrict__ bedges,
    float* __restrict__ outbuf)
{
  constexpr int T = S / 64;
  constexpr int NCHUNK = S / RPB;
  __shared__ float KsT[DH][S];
  __shared__ float VsT[DH][S];
  int bh = blockIdx.x / NCHUNK;
  int chunk = blockIdx.x % NCHUNK;
  int b = bh >> 3, h = bh & 7;
  int tid = threadIdx.x;
  const float* base = qkv + (size_t)b * S * 384;
  // stage K^T, V^T (d-major so per-lane reads are j-contiguous -> conflict-free)
  for (int idx = tid; idx < S * 4; idx += 256) {
    int j = idx >> 2, d4 = idx & 3;
    float4 kv = *(const float4*)(base + (size_t)j*384 + 128 + h*DH + d4*4);
    float4 vv = *(const float4*)(base + (size_t)j*384 + 256 + h*DH + d4*4);
    KsT[d4*4+0][j] = kv.x; KsT[d4*4+1][j] = kv.y;
    KsT[d4*4+2][j] = kv.z; KsT[d4*4+3][j] = kv.w;
    VsT[d4*4+0][j] = vv.x; VsT[d4*4+1][j] = vv.y;
    VsT[d4*4+2][j] = vv.z; VsT[d4*4+3][j] = vv.w;
  }
  __syncthreads();
  int lane = tid & 63, wave = tid >> 6;
  for (int s = chunk * RPB + wave; s < (chunk + 1) * RPB; s += 4) {
    // q broadcast (same 16 floats for all lanes; L1/L2 served)
    const float4* qp = (const float4*)(base + (size_t)s*384 + h*DH);
    float4 q0 = qp[0], q1 = qp[1], q2 = qp[2], q3 = qp[3];
    float q[DH] = {q0.x,q0.y,q0.z,q0.w, q1.x,q1.y,q1.z,q1.w,
                   q2.x,q2.y,q2.z,q2.w, q3.x,q3.y,q3.z,q3.w};
    float sc[T];
    #pragma unroll
    for (int t = 0; t < T; ++t) {
      int j = t * 64 + lane;
      float v = 0.0f;
      #pragma unroll
      for (int d = 0; d < DH; ++d) v += q[d] * KsT[d][j];
      sc[t] = v * 0.25f;   // 1/sqrt(16)
    }
    float mx = sc[0];
    #pragma unroll
    for (int t = 1; t < T; ++t) mx = fmaxf(mx, sc[t]);
    #pragma unroll
    for (int off = 32; off >= 1; off >>= 1) mx = fmaxf(mx, __shfl_xor(mx, off));
    float p[T];
    float l = 0.0f;
    #pragma unroll
    for (int t = 0; t < T; ++t) { p[t] = __expf(sc[t] - mx); l += p[t]; }
    #pragma unroll
    for (int off = 32; off >= 1; off >>= 1) l += __shfl_xor(l, off);
    float o[DH] = {};
    #pragma unroll
    for (int t = 0; t < T; ++t) {
      int j = t * 64 + lane;
      float pt = p[t];
      #pragma unroll
      for (int d = 0; d < DH; ++d) o[d] += pt * VsT[d][j];
    }
    #pragma unroll
    for (int d = 0; d < DH; ++d) {
      #pragma unroll
      for (int off = 32; off >= 1; off >>= 1) o[d] += __shfl_xor(o[d], off);
    }
    if (lane < DH) {
      // select o[lane] without dynamic register indexing
      float val = o[0];
      #pragma unroll
      for (int d = 1; d < DH; ++d) val = (lane == d) ? o[d] : val;
      val *= (1.0f / l);
      if (MODE == 0) {
        int src = bedges[((size_t)b * S + s) * 2];
        atomAddF(&outbuf[(size_t)(b * LBLK + src) * H + h * DH + lane], val);
      } else {
        atomAddF(&outbuf[(size_t)b * H + h * DH + lane], val * (1.0f / 64.0f));
      }
    }
  }
}

__global__ __launch_bounds__(256) void k_scale_bsum(
    float* __restrict__ bsum, const float* __restrict__ cntb,
    float* __restrict__ ind)
{
  int idx = blockIdx.x * 256 + threadIdx.x;   // over NBLKT*H
  int r = idx >> 7;
  float c = cntb[r];
  bsum[idx] = (c > 0.0f) ? bsum[idx] / c : 0.0f;
  if ((idx & 127) == 0) ind[r] = (c > 0.0f) ? 1.0f : 0.0f;
}

// ---------------- final: out-proj + LN + 3-layer MLP ----------------
__device__ __forceinline__ float bsum128(float v, float* red) {
  int t = threadIdx.x;
  red[t] = v; __syncthreads();
  #pragma unroll
  for (int off = 64; off > 0; off >>= 1) {
    if (t < off) red[t] += red[t + off];
    __syncthreads();
  }
  float s = red[0];
  __syncthreads();
  return s;
}

__global__ __launch_bounds__(128) void k_final(
    const float* __restrict__ m2, const float* __restrict__ out_w,
    const float* __restrict__ out_b, const float* __restrict__ lng,
    const float* __restrict__ lnb, const float* __restrict__ w1,
    const float* __restrict__ b1, const float* __restrict__ w2,
    const float* __restrict__ b2, const float* __restrict__ w3,
    const float* __restrict__ b3, float* __restrict__ out)
{
  __shared__ float buf[128];
  __shared__ float red[128];
  int b = blockIdx.x, t = threadIdx.x;
  buf[t] = m2[b*H + t];
  __syncthreads();
  float g = out_b[t];
  for (int k = 0; k < H; ++k) g += buf[k] * out_w[k*H + t];
  float mu = bsum128(g, red) * (1.0f / H);
  float df = g - mu;
  float var = bsum128(df * df, red) * (1.0f / H);
  float gn = df / sqrtf(var + 1e-5f) * lng[t] + lnb[t];
  __syncthreads();
  buf[t] = gn; __syncthreads();
  float h1 = b1[t];
  for (int k = 0; k < H; ++k) h1 += buf[k] * w1[k*H + t];
  h1 = fmaxf(h1, 0.0f);
  __syncthreads();
  buf[t] = h1; __syncthreads();
  float h2 = b2[t];
  for (int k = 0; k < H; ++k) h2 += buf[k] * w2[k*H + t];
  h2 = fmaxf(h2, 0.0f);
  float tot = bsum128(h2 * w3[t], red);
  if (t == 0) out[b] = tot + b3[0];
}

extern "C" void kernel_launch(void* const* d_in, const int* in_sizes, int n_in,
                              void* d_out, int out_size, void* d_ws, size_t ws_size,
                              hipStream_t stream) {
  (void)in_sizes; (void)n_in; (void)out_size; (void)ws_size;
  const int*   A          = (const int*)d_in[0];
  const int*   apos       = (const int*)d_in[1];
  const int*   btypes     = (const int*)d_in[2];
  const float* coords     = (const float*)d_in[3];
  const int*   edge_index = (const int*)d_in[4];
  const int*   bedges     = (const int*)d_in[5];
  const float* emb_atom   = (const float*)d_in[6];
  const float* emb_pos    = (const float*)d_in[7];
  const float* emb_block  = (const float*)d_in[8];
  const float* rbf_freq   = (const float*)d_in[9];
  const float* inter_w1   = (const float*)d_in[10];
  const float* inter_b1   = (const float*)d_in[11];
  const float* inter_w2   = (const float*)d_in[12];
  const float* inter_b2   = (const float*)d_in[13];
  const float* upd_w1     = (const float*)d_in[14];
  const float* upd_b1     = (const float*)d_in[15];
  const float* upd_w2     = (const float*)d_in[16];
  const float* upd_b2     = (const float*)d_in[17];
  const float* edge_w1    = (const float*)d_in[18];
  const float* edge_b1    = (const float*)d_in[19];
  const float* edge_w2    = (const float*)d_in[20];
  const float* edge_b2    = (const float*)d_in[21];
  const float* attn_in_w  = (const float*)d_in[22];
  const float* attn_in_b  = (const float*)d_in[23];
  const float* attn_out_w = (const float*)d_in[24];
  const float* attn_out_b = (const float*)d_in[25];
  const float* ln_g       = (const float*)d_in[26];
  const float* ln_b       = (const float*)d_in[27];
  const float* fin_w1     = (const float*)d_in[28];
  const float* fin_b1     = (const float*)d_in[29];
  const float* fin_w2     = (const float*)d_in[30];
  const float* fin_b2     = (const float*)d_in[31];
  const float* fin_w3     = (const float*)d_in[32];
  const float* fin_b3     = (const float*)d_in[33];
  float* out = (float*)d_out;

  float* ws = (float*)d_ws;
  float* x      = ws + 0;
  float* P      = ws + 2097152;
  float* Q      = ws + 4194304;
  float* Hagg   = ws + 6291456;
  float* rbf    = ws + 8388608;    // E*6
  float* cntf   = ws + 9961472;    // NA
  float* blocks = ws + 9977856;    // NBLKT*H
  float* Pb     = ws + 10108928;
  float* Qb     = ws + 10240000;
  float* Epre   = ws + 10371072;   // BSG*EBE*H
  float* ef2    = ws + 11419648;
  float* qkv    = ws + 12468224;   // BSG*EBE*384 (reused for qkv2)
  float* bsum   = ws + 15613952;   // NBLKT*H
  float* cntb   = ws + 15745024;   // NBLKT
  float* ind    = ws + 15746048;   // NBLKT
  float* m2     = ws + 15747072;   // BSG*H

  const int* ei = edge_index;
  const int* ej = edge_index + NE;

  (void)hipMemsetAsync(cntf, 0, NA * sizeof(float), stream);
  k_embed<<<NA*H/256, 256, 0, stream>>>(A, apos, btypes, emb_atom, emb_pos, emb_block, x);
  k_rbf<<<NE/256, 256, 0, stream>>>(ei, ej, coords, rbf_freq, rbf, cntf);

  for (int b = 0; b < NBI; ++b) {
    const float* w1 = inter_w1 + (size_t)b * 262 * H;
    // P = x@W1a + b1 ; Q = x@W1b
    gemm128<<<NA/32, 256, 0, stream>>>(x, nullptr, w1, H, 0, inter_b1 + b*H,
                                       nullptr, nullptr, P, H, 0, NA, H, 0);
    gemm128<<<NA/32, 256, 0, stream>>>(x, nullptr, w1 + 128*H, H, 0, nullptr,
                                       nullptr, nullptr, Q, H, 0, NA, H, 0);
    (void)hipMemsetAsync(Hagg, 0, (size_t)NA * H * sizeof(float), stream);
    k_edge_pass<<<NE/16, 256, 0, stream>>>(P, Q, rbf, w1 + 256*H, ei, ej, Hagg);
    // agg = Hagg@W2 + cnt*b2  -> into P
    gemm128<<<NA/32, 256, 0, stream>>>(Hagg, nullptr, inter_w2 + (size_t)b*H*H, H, 0,
                                       inter_b2 + b*H, cntf, nullptr, P, H, 0, NA, H, 0);
    // U = silu([x|agg]@upd_w1 + b1) -> into Q
    gemm128<<<NA/32, 256, 0, stream>>>(x, P, upd_w1 + (size_t)b*2*H*H, H, 0,
                                       upd_b1 + b*H, nullptr, nullptr, Q, H, 0, NA, 2*H, 1);
    // x = U@upd_w2 + b2 + x
    gemm128<<<NA/32, 256, 0, stream>>>(Q, nullptr, upd_w2 + (size_t)b*H*H, H, 0,
                                       upd_b2 + b*H, nullptr, x, x, H, 0, NA, H, 0);
  }

  k_block_mean<<<NBLKT*H/256, 256, 0, stream>>>(x, blocks);
  gemm128<<<NBLKT/32, 256, 0, stream>>>(blocks, nullptr, edge_w1, H, 0, edge_b1,
                                        nullptr, nullptr, Pb, H, 0, NBLKT, H, 0);
  gemm128<<<NBLKT/32, 256, 0, stream>>>(blocks, nullptr, edge_w1 + 128*H, H, 0, nullptr,
                                        nullptr, nullptr, Qb, H, 0, NBLKT, H, 0);
  k_gather_pre<<<BSG*EBE*H/256, 256, 0, stream>>>(Pb, Qb, bedges, Epre);
  gemm128<<<BSG*EBE/32, 256, 0, stream>>>(Epre, nullptr, edge_w2, H, 0, edge_b2,
                                          nullptr, nullptr, ef2, H, 0, BSG*EBE, H, 0);
  for (int c0 = 0; c0 < 384; c0 += 128)
    gemm128<<<BSG*EBE/32, 256, 0, stream>>>(ef2, nullptr, attn_in_w, 384, c0,
                                            attn_in_b + c0, nullptr, nullptr,
                                            qkv, 384, c0, BSG*EBE, H, 0);
  (void)hipMemsetAsync(bsum, 0, (size_t)(131072 + 1024 + 1024 + 2048) * sizeof(float), stream);
  k_cntb<<<BSG*EBE/256, 256, 0, stream>>>(bedges, cntb);
  k_attn2<EBE, 128, 0><<<BSG*NHD*(EBE/128), 256, 0, stream>>>(qkv, bedges, bsum);
  k_scale_bsum<<<NBLKT*H/256, 256, 0, stream>>>(bsum, cntb, ind);
  // blocks += (bsum/cnt)@out_w + out_b*[cnt>0]
  gemm128<<<NBLKT/32, 256, 0, stream>>>(bsum, nullptr, attn_out_w, H, 0, attn_out_b,
                                        ind, blocks, blocks, H, 0, NBLKT, H, 0);
  for (int c0 = 0; c0 < 384; c0 += 128)
    gemm128<<<NBLKT/32, 256, 0, stream>>>(blocks, nullptr, attn_in_w, 384, c0,
                                          attn_in_b + c0, nullptr, nullptr,
                                          qkv, 384, c0, NBLKT, H, 0);
  k_attn2<LBLK, 64, 1><<<BSG*NHD, 256, 0, stream>>>(qkv, nullptr, m2);
  k_final<<<BSG, 128, 0, stream>>>(m2, attn_out_w, attn_out_b, ln_g, ln_b,
                                   fin_w1, fin_b1, fin_w2, fin_b2, fin_w3, fin_b3, out);
}